// Round 4
// baseline (253.758 us; speedup 1.0000x reference)
//
#include <hip/hip_runtime.h>
#include <stdint.h>

// ---------------------------------------------------------------------------
// MixingLayer: b=16, m=64, f=128, k=64, L2=16, LMAX=4. ALL I/O IS FP32.
// SEG = [0,1,1,1,2,2,2,2,2,3,3,3,3,3,3,3]
//
// Round-4 structure: G is NEVER materialized in HBM. The fused GEMM
// recomputes each 128x32 A-tile (G values) in-register/LDS per K-step:
//   mx/my[m,n] = sum_kk G[m][kk] * W[n][kk],  kk = fy*512 + fx*4 + l
//   G[m][kk]   = sum_c y[m,fy,c] * x[m,fx,c] * S[c,l]
// Each (m,kk) belongs to exactly one block (M-tile x K-split) -> recompute
// count = 1 (268M MACs total, ~10us VALU), replacing 268MB of HBM traffic.
//
// ws layout (bytes):
//   Wb  bf16 [128 n][65536 kk]   @ 0          (16,777,216)
//   xb  bf16 [1024 m][128 f][16] @ 16777216   ( 4,194,304)
//   yb  bf16 [1024 m][128 f][16] @ 20971520   ( 4,194,304)
//   Cpart f32 [32][1024][128]    @ 25165824   (16,777,216)
//   wfT f32 [2][64 k][4 l][128f] @ 41943040   (   262,144)
// ---------------------------------------------------------------------------

#define AS1 __attribute__((address_space(1)))
#define AS3 __attribute__((address_space(3)))

typedef __bf16 bf16x8 __attribute__((ext_vector_type(8)));
typedef float f32x4 __attribute__((ext_vector_type(4)));

__device__ __forceinline__ uint16_t f2b(float f) {
  uint32_t u = __float_as_uint(f);
  u += 0x7fffu + ((u >> 16) & 1u);   // RNE
  return (uint16_t)(u >> 16);
}

// unpack one dword (2 packed bf16) to 2 floats: lo = bits<<16, hi = bits&mask
__device__ __forceinline__ void up2(uint32_t d, float& lo, float& hi) {
  lo = __uint_as_float(d << 16);
  hi = __uint_as_float(d & 0xffff0000u);
}
__device__ __forceinline__ void up8(uint4 v, float* o) {
  up2(v.x, o[0], o[1]); up2(v.y, o[2], o[3]);
  up2(v.z, o[4], o[5]); up2(v.w, o[6], o[7]);
}

// ---------------------------------------------------------------------------
// K0: one-shot f32 -> bf16 conversions: Wb (wx0|wy0), xb, yb.
// 12,582,912 elements, 8/thread, 6144 blocks x 256. ~50MB traffic.
// ---------------------------------------------------------------------------
__global__ __launch_bounds__(256) void convert_all(
    const float* __restrict__ wx0, const float* __restrict__ wy0,
    const float* __restrict__ x, const float* __restrict__ y,
    uint16_t* __restrict__ Wb, uint16_t* __restrict__ xb,
    uint16_t* __restrict__ yb) {
  size_t i = ((size_t)blockIdx.x * 256 + threadIdx.x) * 8;
  const float* s; uint16_t* d;
  if (i < 4194304)        { s = wx0 + i;              d = Wb + i; }
  else if (i < 8388608)   { s = wy0 + (i - 4194304);  d = Wb + i; }
  else if (i < 10485760)  { s = x + (i - 8388608);    d = xb + (i - 8388608); }
  else                    { s = y + (i - 10485760);   d = yb + (i - 10485760); }
  float4 v0 = *(const float4*)s;
  float4 v1 = *(const float4*)(s + 4);
  uint32_t o0 = (uint32_t)f2b(v0.x) | ((uint32_t)f2b(v0.y) << 16);
  uint32_t o1 = (uint32_t)f2b(v0.z) | ((uint32_t)f2b(v0.w) << 16);
  uint32_t o2 = (uint32_t)f2b(v1.x) | ((uint32_t)f2b(v1.y) << 16);
  uint32_t o3 = (uint32_t)f2b(v1.z) | ((uint32_t)f2b(v1.w) << 16);
  *(uint4*)d = make_uint4(o0, o1, o2, o3);
}

// ---------------------------------------------------------------------------
// K1: FUSED G-gen + split-K GEMM.
// grid (8 M-tiles, 32 splits), block 256 (2x2 waves of 64x64).
// Split s covers fy in {4s..4s+3}; per fy-phase 16 steps of 8 fx (BK=32).
// Per step: stage Wb slab -> sB via global_load_lds; thread (m=t&127,
// half=t>>7) gathers x[m, 4 fx, 16 c] (one 128B line from L2), computes
// 16 G values (64 MACs), packs bf16 -> sA (stride 40 elems: conflict-free
// b128 cadence for both ds_write and a-frag ds_read, 16B-aligned).
// ---------------------------------------------------------------------------
__device__ __forceinline__ void gload_lds16(const void* g, void* l) {
  __builtin_amdgcn_global_load_lds((const AS1 uint32_t*)g, (AS3 uint32_t*)l, 16, 0, 0);
}

__global__ __launch_bounds__(256) void fused_gemm(
    const uint16_t* __restrict__ xb, const uint16_t* __restrict__ yb,
    const uint16_t* __restrict__ Wb, float* __restrict__ Cpart) {
  __shared__ __align__(16) uint16_t sA[128 * 40];   // padded stride 40 (80 B)
  __shared__ __align__(16) uint16_t sB[128 * 32];   // unpadded (global_load_lds)
  const int seg[16] = {0,1,1,1,2,2,2,2,2,3,3,3,3,3,3,3};

  int tid = threadIdx.x;
  int w = tid >> 6, lane = tid & 63;
  int m0 = blockIdx.x * 128;
  int s = blockIdx.y;
  int r = lane & 15, q = lane >> 4;
  int wm = w >> 1, wn = w & 1;
  int rowl = lane >> 2, qq = lane & 3;
  int m_loc = tid & 127, half = tid >> 7;

  const uint16_t* xrow = xb + (size_t)(m0 + m_loc) * 2048;
  const uint16_t* yrow = yb + (size_t)(m0 + m_loc) * 2048;

  f32x4 zero = {0.f, 0.f, 0.f, 0.f};
  f32x4 acc[4][4];
#pragma unroll
  for (int i = 0; i < 4; ++i)
#pragma unroll
    for (int j = 0; j < 4; ++j) acc[i][j] = zero;

  for (int ph = 0; ph < 4; ++ph) {
    int fy = s * 4 + ph;
    // y[m, fy, 0:16] -> registers for this phase
    float yreg[16];
    {
      uint4 v0 = *(const uint4*)(yrow + fy * 16);
      uint4 v1 = *(const uint4*)(yrow + fy * 16 + 8);
      up8(v0, yreg); up8(v1, yreg + 8);
    }

    for (int ks = 0; ks < 16; ++ks) {
      int kk0 = fy * 512 + ks * 32;
      __syncthreads();  // previous step's LDS consumption done

      // stage B slab (128 n x 32 kk bf16, 8 KB) via global_load_lds
#pragma unroll
      for (int jj = 0; jj < 2; ++jj) {
        int blk = w * 2 + jj;           // wave-uniform
        int rowi = blk * 16 + rowl;
        gload_lds16(Wb + (size_t)rowi * 65536 + kk0 + qq * 8, &sB[blk * 512]);
      }

      // G-gen: this thread owns (m = m_loc, fx = ks*8 + half*4 + fxp, all l)
      const uint16_t* xp = xrow + (ks * 8 + half * 4) * 16;  // 64 bf16, one 128B line
      float g[16];
#pragma unroll
      for (int p = 0; p < 16; ++p) g[p] = 0.f;
#pragma unroll
      for (int fxp = 0; fxp < 4; ++fxp) {
        uint4 v0 = *(const uint4*)(xp + fxp * 16);
        uint4 v1 = *(const uint4*)(xp + fxp * 16 + 8);
        float xv[16];
        up8(v0, xv); up8(v1, xv + 8);
#pragma unroll
        for (int c = 0; c < 16; ++c)
          g[fxp * 4 + seg[c]] += yreg[c] * xv[c];
      }
      // pack 16 f32 -> 8 dwords (truncation; error margin is huge)
      uint32_t o[8];
#pragma unroll
      for (int p = 0; p < 8; ++p)
        o[p] = (__float_as_uint(g[2 * p]) >> 16) |
               (__float_as_uint(g[2 * p + 1]) & 0xffff0000u);
      uint16_t* dstA = &sA[m_loc * 40 + half * 16];
      *(uint4*)dstA       = make_uint4(o[0], o[1], o[2], o[3]);
      *(uint4*)(dstA + 8) = make_uint4(o[4], o[5], o[6], o[7]);

      __syncthreads();  // sA written, sB DMA drained (vmcnt0 at barrier)

      bf16x8 a[4], b[4];
#pragma unroll
      for (int i = 0; i < 4; ++i)
        a[i] = *(const bf16x8*)&sA[(wm * 64 + i * 16 + r) * 40 + q * 8];
#pragma unroll
      for (int j = 0; j < 4; ++j)
        b[j] = *(const bf16x8*)&sB[(wn * 64 + j * 16 + r) * 32 + q * 8];
#pragma unroll
      for (int i = 0; i < 4; ++i)
#pragma unroll
        for (int j = 0; j < 4; ++j)
          acc[i][j] = __builtin_amdgcn_mfma_f32_16x16x32_bf16(a[i], b[j], acc[i][j], 0, 0, 0);
    }
  }

  // C/D layout: col(n)=lane&15, row(m)=(lane>>4)*4+reg
  float* cbase = Cpart + (size_t)blockIdx.y * 131072;  // 1024*128
#pragma unroll
  for (int i = 0; i < 4; ++i)
#pragma unroll
    for (int j = 0; j < 4; ++j)
#pragma unroll
      for (int reg = 0; reg < 4; ++reg) {
        int mm = m0 + wm * 64 + i * 16 + q * 4 + reg;
        int nn = wn * 64 + j * 16 + r;
        cbase[(size_t)mm * 128 + nn] = acc[i][j][reg];
      }
}

// ---------------------------------------------------------------------------
// K2: wfT[((side*64+k)*4+l)*128+f] = wf_side[(l*128+f)*64+k]  (256 KB)
// ---------------------------------------------------------------------------
__global__ __launch_bounds__(256) void wft_kernel(const float* __restrict__ wxf,
                                                  const float* __restrict__ wyf,
                                                  float* __restrict__ wfT) {
  int idx = blockIdx.x * 256 + threadIdx.x;   // 65536 total
  int side = idx >> 15;
  int rem = idx & 32767;
  int k = rem >> 9;
  int l = (rem >> 7) & 3;
  int f = rem & 127;
  const float* src = side ? wyf : wxf;
  wfT[idx] = src[((size_t)l * 128 + f) * 64 + k];
}

// ---------------------------------------------------------------------------
// K3: ONE BLOCK PER bm (1024 blocks, 256 thr).
//   reduce 32 partials -> sm[128] (mx|my); 2 MLP stages (bias[st][m][j],
//   m = bm&63!); gates via wfT (coalesced); fused elementwise output.
// ---------------------------------------------------------------------------
__global__ __launch_bounds__(256) void finish_kernel(
    const float* __restrict__ x, const float* __restrict__ y,
    const float* __restrict__ wx_mlp, const float* __restrict__ bx_mlp,
    const float* __restrict__ wy_mlp, const float* __restrict__ by_mlp,
    const float* __restrict__ wfT,
    const float* __restrict__ Cpart, float* __restrict__ out) {
  const int seg[16] = {0,1,1,1,2,2,2,2,2,3,3,3,3,3,3,3};
  __shared__ float sm[128];
  __shared__ float sg[2][128][4];
  int t = threadIdx.x;
  int bm = blockIdx.x;
  int mi = bm & 63;

  if (t < 128) {
    float ssum = 0.f;
#pragma unroll
    for (int sp = 0; sp < 32; ++sp)
      ssum += Cpart[(size_t)sp * 131072 + (size_t)bm * 128 + t];
    sm[t] = ssum;  // [0:64)=mx, [64:128)=my
  }
  __syncthreads();

  for (int st = 0; st < 2; ++st) {
    float v = 0.f;
    if (t < 128) {
      int side = t >> 6, j = t & 63;
      const float* wmlp = side ? wy_mlp : wx_mlp;
      const float* bmlp = side ? by_mlp : bx_mlp;
      const float* mv = sm + side * 64;
#pragma unroll 8
      for (int k = 0; k < 64; ++k)
        v += mv[k] * wmlp[(st * 64 + k) * 64 + j];
      v += bmlp[(st * 64 + mi) * 64 + j];
      v = v / (1.f + __expf(-v));
    }
    __syncthreads();
    if (t < 128) sm[t] = v;
    __syncthreads();
  }

  {
    int side = t >> 7, f = t & 127;
    const float* base = wfT + side * 32768;  // [k][l][f]
    const float* mv = sm + side * 64;
    float g[4] = {0.f, 0.f, 0.f, 0.f};
#pragma unroll 8
    for (int k = 0; k < 64; ++k) {
      float m2 = mv[k];
#pragma unroll
      for (int l = 0; l < 4; ++l)
        g[l] += m2 * base[(k * 4 + l) * 128 + f];
    }
#pragma unroll
    for (int l = 0; l < 4; ++l)
      sg[side][f][l] = g[l] / (1.f + __expf(-g[l]));
  }
  __syncthreads();

  {
    int f = t >> 1, half = t & 1;
    size_t base = ((size_t)bm * 128 + f) * 16 + half * 8;
    float4 xa = *(const float4*)(x + base), xb4 = *(const float4*)(x + base + 4);
    float4 ya = *(const float4*)(y + base), yb4 = *(const float4*)(y + base + 4);
    float xv[8] = {xa.x, xa.y, xa.z, xa.w, xb4.x, xb4.y, xb4.z, xb4.w};
    float yv[8] = {ya.x, ya.y, ya.z, ya.w, yb4.x, yb4.y, yb4.z, yb4.w};
    float o[8];
#pragma unroll
    for (int ii = 0; ii < 8; ++ii) {
      int c = half * 8 + ii;
      o[ii] = sg[0][f][seg[c]] * xv[ii] + sg[1][f][seg[c]] * yv[ii];
    }
    *(float4*)(out + base)     = make_float4(o[0], o[1], o[2], o[3]);
    *(float4*)(out + base + 4) = make_float4(o[4], o[5], o[6], o[7]);
  }
}

// ---------------------------------------------------------------------------
extern "C" void kernel_launch(void* const* d_in, const int* in_sizes, int n_in,
                              void* d_out, int out_size, void* d_ws, size_t ws_size,
                              hipStream_t stream) {
  const float* x      = (const float*)d_in[0];
  const float* y      = (const float*)d_in[1];
  const float* wx0    = (const float*)d_in[2];
  const float* wy0    = (const float*)d_in[3];
  const float* wx_mlp = (const float*)d_in[4];
  const float* bx_mlp = (const float*)d_in[5];
  const float* wy_mlp = (const float*)d_in[6];
  const float* by_mlp = (const float*)d_in[7];
  const float* wxf    = (const float*)d_in[8];
  const float* wyf    = (const float*)d_in[9];
  float* out = (float*)d_out;

  uint16_t* Wb    = (uint16_t*)d_ws;                               // 16,777,216 B
  uint16_t* xb    = (uint16_t*)((char*)d_ws + (size_t)16777216);   //  4,194,304 B
  uint16_t* yb    = (uint16_t*)((char*)d_ws + (size_t)20971520);   //  4,194,304 B
  float*    Cpart = (float*)((char*)d_ws + (size_t)25165824);      // 16,777,216 B
  float*    wfT   = (float*)((char*)d_ws + (size_t)41943040);      //    262,144 B

  convert_all<<<6144, 256, 0, stream>>>(wx0, wy0, x, y, Wb, xb, yb);
  fused_gemm<<<dim3(8, 32), 256, 0, stream>>>(xb, yb, Wb, Cpart);
  wft_kernel<<<256, 256, 0, stream>>>(wxf, wyf, wfT);
  finish_kernel<<<1024, 256, 0, stream>>>(x, y, wx_mlp, bx_mlp, wy_mlp, by_mlp,
                                          wfT, Cpart, out);
}

// Round 5
// 212.320 us; speedup vs baseline: 1.1952x; 1.1952x over previous
//
#include <hip/hip_runtime.h>
#include <stdint.h>

// ---------------------------------------------------------------------------
// MixingLayer: b=16, m=64, f=128, k=64, L2=16, LMAX=4. ALL I/O IS FP32.
// SEG = [0,1,1,1,2,2,2,2,2,3,3,3,3,3,3,3]
//
// G is never materialized. fused_gemm recomputes the 128x32 A-tile per step:
//   mx/my[m,n] = sum_kk G[m][kk] * W[n][kk],  kk = fy*512 + fx*4 + l
//   G[m][kk]   = sum_c y[m,fy,c] * x[m,fx,c] * S[c,l]
// Round-5 changes vs round-4 (which was DMA-latency-bound at 1 block/CU):
//   * grid (8 M-tiles x 64 splits) = 512 blocks -> 2 blocks/CU overlap
//   * double-buffered sA/sB, ONE barrier per step; B-DMA and G-gen for
//     step t+1 issued/computed during step t's MFMA.
//
// ws layout (bytes):
//   Wb  bf16 [128 n][65536 kk]   @ 0          (16,777,216)
//   xb  bf16 [1024 m][128 f][16] @ 16777216   ( 4,194,304)
//   yb  bf16 [1024 m][128 f][16] @ 20971520   ( 4,194,304)
//   Cpart f32 [64][1024][128]    @ 25165824   (33,554,432)
//   wfT f32 [2][64 k][4 l][128f] @ 58720256   (   262,144)
// ---------------------------------------------------------------------------

#define AS1 __attribute__((address_space(1)))
#define AS3 __attribute__((address_space(3)))

typedef __bf16 bf16x8 __attribute__((ext_vector_type(8)));
typedef float f32x4 __attribute__((ext_vector_type(4)));

__device__ __forceinline__ uint16_t f2b(float f) {
  uint32_t u = __float_as_uint(f);
  u += 0x7fffu + ((u >> 16) & 1u);   // RNE
  return (uint16_t)(u >> 16);
}

__device__ __forceinline__ void up2(uint32_t d, float& lo, float& hi) {
  lo = __uint_as_float(d << 16);
  hi = __uint_as_float(d & 0xffff0000u);
}
__device__ __forceinline__ void up8(uint4 v, float* o) {
  up2(v.x, o[0], o[1]); up2(v.y, o[2], o[3]);
  up2(v.z, o[4], o[5]); up2(v.w, o[6], o[7]);
}

// ---------------------------------------------------------------------------
// K0: one-shot f32 -> bf16 conversions: Wb (wx0|wy0), xb, yb.
// ---------------------------------------------------------------------------
__global__ __launch_bounds__(256) void convert_all(
    const float* __restrict__ wx0, const float* __restrict__ wy0,
    const float* __restrict__ x, const float* __restrict__ y,
    uint16_t* __restrict__ Wb, uint16_t* __restrict__ xb,
    uint16_t* __restrict__ yb) {
  size_t i = ((size_t)blockIdx.x * 256 + threadIdx.x) * 8;
  const float* s; uint16_t* d;
  if (i < 4194304)        { s = wx0 + i;              d = Wb + i; }
  else if (i < 8388608)   { s = wy0 + (i - 4194304);  d = Wb + i; }
  else if (i < 10485760)  { s = x + (i - 8388608);    d = xb + (i - 8388608); }
  else                    { s = y + (i - 10485760);   d = yb + (i - 10485760); }
  float4 v0 = *(const float4*)s;
  float4 v1 = *(const float4*)(s + 4);
  uint32_t o0 = (uint32_t)f2b(v0.x) | ((uint32_t)f2b(v0.y) << 16);
  uint32_t o1 = (uint32_t)f2b(v0.z) | ((uint32_t)f2b(v0.w) << 16);
  uint32_t o2 = (uint32_t)f2b(v1.x) | ((uint32_t)f2b(v1.y) << 16);
  uint32_t o3 = (uint32_t)f2b(v1.z) | ((uint32_t)f2b(v1.w) << 16);
  *(uint4*)d = make_uint4(o0, o1, o2, o3);
}

// ---------------------------------------------------------------------------
// K1: FUSED G-gen + split-K GEMM, double-buffered, 1 barrier/step.
// grid (8, 64): M-tile 128, split = 2 fy (32 steps of BK=32 kk).
// step t: fy = 2*s + (t>>4), fx block = (t&15)*8.
// ---------------------------------------------------------------------------
__device__ __forceinline__ void gload_lds16(const void* g, void* l) {
  __builtin_amdgcn_global_load_lds((const AS1 uint32_t*)g, (AS3 uint32_t*)l, 16, 0, 0);
}

__global__ __launch_bounds__(256, 2) void fused_gemm(
    const uint16_t* __restrict__ xb, const uint16_t* __restrict__ yb,
    const uint16_t* __restrict__ Wb, float* __restrict__ Cpart) {
  __shared__ __align__(16) uint16_t sA[2][128 * 40];  // padded stride 40
  __shared__ __align__(16) uint16_t sB[2][128 * 32];
  const int seg[16] = {0,1,1,1,2,2,2,2,2,3,3,3,3,3,3,3};

  int tid = threadIdx.x;
  int w = tid >> 6, lane = tid & 63;
  int m0 = blockIdx.x * 128;
  int s = blockIdx.y;
  int r = lane & 15, q = lane >> 4;
  int wm = w >> 1, wn = w & 1;
  int rowl = lane >> 2, qq = lane & 3;
  int m_loc = tid & 127, half = tid >> 7;

  const uint16_t* xrow = xb + (size_t)(m0 + m_loc) * 2048;
  const uint16_t* yrow = yb + (size_t)(m0 + m_loc) * 2048;

  // both fy phases' y -> registers
  float yreg[2][16];
#pragma unroll
  for (int ph = 0; ph < 2; ++ph) {
    uint4 v0 = *(const uint4*)(yrow + (2 * s + ph) * 16);
    uint4 v1 = *(const uint4*)(yrow + (2 * s + ph) * 16 + 8);
    up8(v0, yreg[ph]); up8(v1, yreg[ph] + 8);
  }

  f32x4 zero = {0.f, 0.f, 0.f, 0.f};
  f32x4 acc[4][4];
#pragma unroll
  for (int i = 0; i < 4; ++i)
#pragma unroll
    for (int j = 0; j < 4; ++j) acc[i][j] = zero;

  auto issueB = [&](int buf, int t) {
    int kk0 = (2 * s + (t >> 4)) * 512 + (t & 15) * 32;
#pragma unroll
    for (int jj = 0; jj < 2; ++jj) {
      int blk = w * 2 + jj;  // wave-uniform
      int rowi = blk * 16 + rowl;
      gload_lds16(Wb + (size_t)rowi * 65536 + kk0 + qq * 8, &sB[buf][blk * 512]);
    }
  };
  auto computeG = [&](int t, float* g) {
    const uint16_t* xp = xrow + ((t & 15) * 8 + half * 4) * 16;  // 128B line
    const float* yr = yreg[t >> 4];
#pragma unroll
    for (int p = 0; p < 16; ++p) g[p] = 0.f;
#pragma unroll
    for (int fxp = 0; fxp < 4; ++fxp) {
      uint4 v0 = *(const uint4*)(xp + fxp * 16);
      uint4 v1 = *(const uint4*)(xp + fxp * 16 + 8);
      float xv[16];
      up8(v0, xv); up8(v1, xv + 8);
#pragma unroll
      for (int c = 0; c < 16; ++c)
        g[fxp * 4 + seg[c]] += yr[c] * xv[c];
    }
  };
  auto writeA = [&](int buf, const float* g) {
    uint32_t o[8];
#pragma unroll
    for (int p = 0; p < 8; ++p)
      o[p] = (__float_as_uint(g[2 * p]) >> 16) |
             (__float_as_uint(g[2 * p + 1]) & 0xffff0000u);
    uint16_t* dst = &sA[buf][m_loc * 40 + half * 16];
    *(uint4*)dst       = make_uint4(o[0], o[1], o[2], o[3]);
    *(uint4*)(dst + 8) = make_uint4(o[4], o[5], o[6], o[7]);
  };

  // prologue: fill buffer 0 for step 0
  float g[16];
  issueB(0, 0);
  computeG(0, g);
  writeA(0, g);
  __syncthreads();  // drains DMA (vmcnt0) + LDS writes

  for (int t = 0; t < 32; ++t) {
    int cur = t & 1, nxt = cur ^ 1;
    if (t < 31) {
      issueB(nxt, t + 1);      // DMA in flight across this step's compute
      computeG(t + 1, g);
      writeA(nxt, g);
    }
    bf16x8 a[4], b[4];
#pragma unroll
    for (int i = 0; i < 4; ++i)
      a[i] = *(const bf16x8*)&sA[cur][(wm * 64 + i * 16 + r) * 40 + q * 8];
#pragma unroll
    for (int j = 0; j < 4; ++j)
      b[j] = *(const bf16x8*)&sB[cur][(wn * 64 + j * 16 + r) * 32 + q * 8];
#pragma unroll
    for (int i = 0; i < 4; ++i)
#pragma unroll
      for (int j = 0; j < 4; ++j)
        acc[i][j] = __builtin_amdgcn_mfma_f32_16x16x32_bf16(a[i], b[j], acc[i][j], 0, 0, 0);
    __syncthreads();  // one barrier per step: separates reads(cur) from next writes
  }

  // C/D layout: col(n)=lane&15, row(m)=(lane>>4)*4+reg
  float* cbase = Cpart + (size_t)blockIdx.y * 131072;  // 1024*128
#pragma unroll
  for (int i = 0; i < 4; ++i)
#pragma unroll
    for (int j = 0; j < 4; ++j)
#pragma unroll
      for (int reg = 0; reg < 4; ++reg) {
        int mm = m0 + wm * 64 + i * 16 + q * 4 + reg;
        int nn = wn * 64 + j * 16 + r;
        cbase[(size_t)mm * 128 + nn] = acc[i][j][reg];
      }
}

// ---------------------------------------------------------------------------
// K2: wfT[((side*64+k)*4+l)*128+f] = wf_side[(l*128+f)*64+k]  (256 KB)
// ---------------------------------------------------------------------------
__global__ __launch_bounds__(256) void wft_kernel(const float* __restrict__ wxf,
                                                  const float* __restrict__ wyf,
                                                  float* __restrict__ wfT) {
  int idx = blockIdx.x * 256 + threadIdx.x;   // 65536 total
  int side = idx >> 15;
  int rem = idx & 32767;
  int k = rem >> 9;
  int l = (rem >> 7) & 3;
  int f = rem & 127;
  const float* src = side ? wyf : wxf;
  wfT[idx] = src[((size_t)l * 128 + f) * 64 + k];
}

// ---------------------------------------------------------------------------
// K3: ONE BLOCK PER bm (1024 blocks): reduce 64 splits (all 256 threads),
// 2 MLP stages (bias[st][m][j], m=bm&63), gates via wfT, fused output.
// ---------------------------------------------------------------------------
__global__ __launch_bounds__(256) void finish_kernel(
    const float* __restrict__ x, const float* __restrict__ y,
    const float* __restrict__ wx_mlp, const float* __restrict__ bx_mlp,
    const float* __restrict__ wy_mlp, const float* __restrict__ by_mlp,
    const float* __restrict__ wfT,
    const float* __restrict__ Cpart, float* __restrict__ out) {
  const int seg[16] = {0,1,1,1,2,2,2,2,2,3,3,3,3,3,3,3};
  __shared__ float sred[256];
  __shared__ float sm[128];
  __shared__ float sg[2][128][4];
  int t = threadIdx.x;
  int bm = blockIdx.x;
  int mi = bm & 63;

  {  // split-K reduce with all 256 threads
    int col = t & 127, hh = t >> 7;
    float ssum = 0.f;
#pragma unroll
    for (int sp = hh * 32; sp < hh * 32 + 32; ++sp)
      ssum += Cpart[(size_t)sp * 131072 + (size_t)bm * 128 + col];
    sred[t] = ssum;
  }
  __syncthreads();
  if (t < 128) sm[t] = sred[t] + sred[t + 128];  // [0:64)=mx, [64:128)=my
  __syncthreads();

  for (int st = 0; st < 2; ++st) {
    float v = 0.f;
    if (t < 128) {
      int side = t >> 6, j = t & 63;
      const float* wmlp = side ? wy_mlp : wx_mlp;
      const float* bmlp = side ? by_mlp : bx_mlp;
      const float* mv = sm + side * 64;
#pragma unroll 8
      for (int k = 0; k < 64; ++k)
        v += mv[k] * wmlp[(st * 64 + k) * 64 + j];
      v += bmlp[(st * 64 + mi) * 64 + j];
      v = v / (1.f + __expf(-v));
    }
    __syncthreads();
    if (t < 128) sm[t] = v;
    __syncthreads();
  }

  {  // gates: side wave-uniform, coalesced wfT reads
    int side = t >> 7, f = t & 127;
    const float* base = wfT + side * 32768;  // [k][l][f]
    const float* mv = sm + side * 64;
    float g[4] = {0.f, 0.f, 0.f, 0.f};
#pragma unroll 8
    for (int k = 0; k < 64; ++k) {
      float m2 = mv[k];
#pragma unroll
      for (int l = 0; l < 4; ++l)
        g[l] += m2 * base[(k * 4 + l) * 128 + f];
    }
#pragma unroll
    for (int l = 0; l < 4; ++l)
      sg[side][f][l] = g[l] / (1.f + __expf(-g[l]));
  }
  __syncthreads();

  {  // output: thread -> (f, half), 8 floats; fully coalesced
    int f = t >> 1, half = t & 1;
    size_t base = ((size_t)bm * 128 + f) * 16 + half * 8;
    float4 xa = *(const float4*)(x + base), xb4 = *(const float4*)(x + base + 4);
    float4 ya = *(const float4*)(y + base), yb4 = *(const float4*)(y + base + 4);
    float xv[8] = {xa.x, xa.y, xa.z, xa.w, xb4.x, xb4.y, xb4.z, xb4.w};
    float yv[8] = {ya.x, ya.y, ya.z, ya.w, yb4.x, yb4.y, yb4.z, yb4.w};
    float o[8];
#pragma unroll
    for (int ii = 0; ii < 8; ++ii) {
      int c = half * 8 + ii;
      o[ii] = sg[0][f][seg[c]] * xv[ii] + sg[1][f][seg[c]] * yv[ii];
    }
    *(float4*)(out + base)     = make_float4(o[0], o[1], o[2], o[3]);
    *(float4*)(out + base + 4) = make_float4(o[4], o[5], o[6], o[7]);
  }
}

// ---------------------------------------------------------------------------
extern "C" void kernel_launch(void* const* d_in, const int* in_sizes, int n_in,
                              void* d_out, int out_size, void* d_ws, size_t ws_size,
                              hipStream_t stream) {
  const float* x      = (const float*)d_in[0];
  const float* y      = (const float*)d_in[1];
  const float* wx0    = (const float*)d_in[2];
  const float* wy0    = (const float*)d_in[3];
  const float* wx_mlp = (const float*)d_in[4];
  const float* bx_mlp = (const float*)d_in[5];
  const float* wy_mlp = (const float*)d_in[6];
  const float* by_mlp = (const float*)d_in[7];
  const float* wxf    = (const float*)d_in[8];
  const float* wyf    = (const float*)d_in[9];
  float* out = (float*)d_out;

  uint16_t* Wb    = (uint16_t*)d_ws;                               // 16,777,216 B
  uint16_t* xb    = (uint16_t*)((char*)d_ws + (size_t)16777216);   //  4,194,304 B
  uint16_t* yb    = (uint16_t*)((char*)d_ws + (size_t)20971520);   //  4,194,304 B
  float*    Cpart = (float*)((char*)d_ws + (size_t)25165824);      // 33,554,432 B
  float*    wfT   = (float*)((char*)d_ws + (size_t)58720256);      //    262,144 B

  convert_all<<<6144, 256, 0, stream>>>(wx0, wy0, x, y, Wb, xb, yb);
  fused_gemm<<<dim3(8, 64), 256, 0, stream>>>(xb, yb, Wb, Cpart);
  wft_kernel<<<256, 256, 0, stream>>>(wxf, wyf, wfT);
  finish_kernel<<<1024, 256, 0, stream>>>(x, y, wx_mlp, bx_mlp, wy_mlp, by_mlp,
                                          wfT, Cpart, out);
}